// Round 1
// baseline (102.773 us; speedup 1.0000x reference)
//
#include <hip/hip_runtime.h>

namespace {
constexpr int Wd = 160;
constexpr int Hd = 192;
constexpr int Dd = 160;
constexpr int Bd = 2;
constexpr int VEC = 4;
constexpr int WSTRIPS = Wd / VEC;          // 40
constexpr int COLS = Bd * Hd * WSTRIPS;    // 15360
constexpr int THREADS = 256;
constexpr int COLBLOCKS = COLS / THREADS;  // 60
constexpr int DCHUNK = 16;
constexpr int NCHUNK = Dd / DCHUNK;        // 10
constexpr float EPS = 1e-8f;
}

// Per-slice separable partials for a 4-wide w strip:
//   A = Sh*Sw x   (feeds gz via d-derivative)
//   B = Sh*Dw x   (feeds gx via d-smooth)
//   C = Dh*Sw x   (feeds gy via d-smooth)
__device__ __forceinline__ void compute_abc(const float* __restrict__ base,
                                            int d, int h, int w0,
                                            float A[VEC], float Bv[VEC], float Cv[VEC]) {
  if ((unsigned)d >= (unsigned)Dd) {
#pragma unroll
    for (int j = 0; j < VEC; ++j) { A[j] = 0.f; Bv[j] = 0.f; Cv[j] = 0.f; }
    return;
  }
  const float* slice = base + (size_t)d * (size_t)(Hd * Wd);
  float sw[3][VEC], dwv[3][VEC];
#pragma unroll
  for (int r = 0; r < 3; ++r) {
    int hh = h - 1 + r;
    if ((unsigned)hh >= (unsigned)Hd) {
#pragma unroll
      for (int j = 0; j < VEC; ++j) { sw[r][j] = 0.f; dwv[r][j] = 0.f; }
      continue;
    }
    const float* row = slice + (size_t)hh * Wd + w0;
    const float4 m = *reinterpret_cast<const float4*>(row);  // w0 % 4 == 0 -> 16B aligned
    const float xl = (w0 > 0) ? row[-1] : 0.f;               // SAME zero pad
    const float xr = (w0 + VEC < Wd) ? row[VEC] : 0.f;
    const float x[6] = {xl, m.x, m.y, m.z, m.w, xr};
#pragma unroll
    for (int j = 0; j < VEC; ++j) {
      sw[r][j]  = x[j] + 2.f * x[j + 1] + x[j + 2];
      dwv[r][j] = x[j + 2] - x[j];
    }
  }
#pragma unroll
  for (int j = 0; j < VEC; ++j) {
    A[j]  = sw[0][j] + 2.f * sw[1][j] + sw[2][j];
    Bv[j] = dwv[0][j] + 2.f * dwv[1][j] + dwv[2][j];
    Cv[j] = sw[2][j] - sw[0][j];
  }
}

__global__ __launch_bounds__(THREADS) void sobel_loss_kernel(
    const float* __restrict__ pred, const float* __restrict__ targ,
    float* __restrict__ out) {
  const int col  = blockIdx.x * THREADS + threadIdx.x;
  const int ws   = col % WSTRIPS;
  const int rest = col / WSTRIPS;
  const int h    = rest % Hd;
  const int b    = rest / Hd;
  const int w0   = ws * VEC;
  const int d0   = blockIdx.y * DCHUNK;

  const size_t volOff = (size_t)b * Dd * (size_t)(Hd * Wd);
  const float* pb = pred + volOff;
  const float* tb = targ + volOff;

  float pA0[VEC], pB0[VEC], pC0[VEC], pA1[VEC], pB1[VEC], pC1[VEC],
        pA2[VEC], pB2[VEC], pC2[VEC];
  float tA0[VEC], tB0[VEC], tC0[VEC], tA1[VEC], tB1[VEC], tC1[VEC],
        tA2[VEC], tB2[VEC], tC2[VEC];

  compute_abc(pb, d0 - 1, h, w0, pA0, pB0, pC0);
  compute_abc(pb, d0,     h, w0, pA1, pB1, pC1);
  compute_abc(tb, d0 - 1, h, w0, tA0, tB0, tC0);
  compute_abc(tb, d0,     h, w0, tA1, tB1, tC1);

  float acc = 0.f;
#pragma unroll 4
  for (int d = d0; d < d0 + DCHUNK; ++d) {
    compute_abc(pb, d + 1, h, w0, pA2, pB2, pC2);
    compute_abc(tb, d + 1, h, w0, tA2, tB2, tC2);
#pragma unroll
    for (int j = 0; j < VEC; ++j) {
      float gx = pB0[j] + 2.f * pB1[j] + pB2[j];
      float gy = pC0[j] + 2.f * pC1[j] + pC2[j];
      float gz = pA2[j] - pA0[j];
      const float pm = sqrtf(fmaf(gx, gx, fmaf(gy, gy, fmaf(gz, gz, EPS))));
      gx = tB0[j] + 2.f * tB1[j] + tB2[j];
      gy = tC0[j] + 2.f * tC1[j] + tC2[j];
      gz = tA2[j] - tA0[j];
      const float tm = sqrtf(fmaf(gx, gx, fmaf(gy, gy, fmaf(gz, gz, EPS))));
      acc += fabsf(pm - tm);
    }
    // rotate rolling slices (compile-time indices only)
#pragma unroll
    for (int j = 0; j < VEC; ++j) {
      pA0[j] = pA1[j]; pB0[j] = pB1[j]; pC0[j] = pC1[j];
      pA1[j] = pA2[j]; pB1[j] = pB2[j]; pC1[j] = pC2[j];
      tA0[j] = tA1[j]; tB0[j] = tB1[j]; tC0[j] = tC1[j];
      tA1[j] = tA2[j]; tB1[j] = tB2[j]; tC1[j] = tC2[j];
    }
  }

  // block reduction: wave shfl -> LDS -> one atomic per block
  float s = acc;
#pragma unroll
  for (int off = 32; off > 0; off >>= 1) s += __shfl_down(s, off, 64);
  __shared__ float wsum[THREADS / 64];
  const int lane = threadIdx.x & 63;
  const int wid  = threadIdx.x >> 6;
  if (lane == 0) wsum[wid] = s;
  __syncthreads();
  if (threadIdx.x == 0) {
    float t = 0.f;
#pragma unroll
    for (int i = 0; i < THREADS / 64; ++i) t += wsum[i];
    atomicAdd(out, t * (1.0f / (float)((size_t)Bd * Dd * Hd * Wd)));
  }
}

extern "C" void kernel_launch(void* const* d_in, const int* in_sizes, int n_in,
                              void* d_out, int out_size, void* d_ws, size_t ws_size,
                              hipStream_t stream) {
  const float* pred = (const float*)d_in[0];
  const float* targ = (const float*)d_in[1];
  float* out = (float*)d_out;
  (void)in_sizes; (void)n_in; (void)out_size; (void)d_ws; (void)ws_size;

  hipMemsetAsync(out, 0, sizeof(float), stream);
  dim3 grid(COLBLOCKS, NCHUNK);
  sobel_loss_kernel<<<grid, THREADS, 0, stream>>>(pred, targ, out);
}

// Round 2
// 46.345 us; speedup vs baseline: 2.2176x; 2.2176x over previous
//
#include <hip/hip_runtime.h>

namespace {
constexpr int Wd = 160, Hd = 192, Dd = 160, Bd = 2;
constexpr int HW = Hd * Wd;
constexpr int THREADS = 256;
constexpr int ROWS_OUT = 6;               // output rows per block
constexpr int ROWS_LDS = 8;               // staged rows incl. h-halo
constexpr int RS = 168;                   // LDS row stride in floats (data at [4..163], pads at 3,164)
constexpr int STRIPS = Wd / 4;            // 40 float4 strips per row
constexpr int CTHREADS = ROWS_OUT * STRIPS;  // 240 compute threads
constexpr int SLOTS = 2 * ROWS_LDS * STRIPS; // 640 staging float4 slots (2 tensors)
constexpr int DCHUNK = 10;
constexpr int NCHUNK = Dd / DCHUNK;       // 16
constexpr int RGROUPS = Hd / ROWS_OUT;    // 32
constexpr float EPS = 1e-8f;
}

__global__ __launch_bounds__(THREADS) void sobel_loss_kernel(
    const float* __restrict__ pred, const float* __restrict__ targ,
    float* __restrict__ out) {
  __shared__ float lds[2][ROWS_LDS][RS];
  const int tid = threadIdx.x;
  const int h0 = blockIdx.x * ROWS_OUT;
  const int d0 = blockIdx.y * DCHUNK;
  const size_t volOff = (size_t)blockIdx.z * Dd * HW;
  const float* pb = pred + volOff;
  const float* tb = targ + volOff;

  // zero the w-halo pad columns once (never overwritten)
  if (tid < 2 * ROWS_LDS) {
    const int t_ = tid >> 3, r8 = tid & 7;
    lds[t_][r8][3] = 0.f;
    lds[t_][r8][164] = 0.f;
  }

  // ---- staging slot decode (loop-invariant) ----
  const float* gs[3];
  float* dst[3];
  bool rok[3], sok[3];
#pragma unroll
  for (int u = 0; u < 3; ++u) {
    const int i = tid + 256 * u;
    const bool ok = (i < SLOTS);
    const int ic = ok ? i : 0;
    const int t_ = ic >= SLOTS / 2;
    const int idx = ic - (t_ ? SLOTS / 2 : 0);
    const int r8 = idx / STRIPS, s = idx - r8 * STRIPS;
    const int hh = h0 - 1 + r8;
    const bool rv = ok && ((unsigned)hh < (unsigned)Hd);
    rok[u] = rv;
    sok[u] = ok;
    gs[u] = (t_ ? tb : pb) + (size_t)(rv ? hh : 0) * Wd + s * 4;
    dst[u] = &lds[t_][r8][4 + s * 4];
  }

  float4 rg[3];
  auto GLOAD = [&](int dsl) {
    const bool dok = (unsigned)dsl < (unsigned)Dd;
    const size_t so = (size_t)dsl * HW;
#pragma unroll
    for (int u = 0; u < 3; ++u) {
      float4 v = make_float4(0.f, 0.f, 0.f, 0.f);
      if (dok && rok[u]) v = *reinterpret_cast<const float4*>(gs[u] + so);
      rg[u] = v;
    }
  };
  auto DSW = [&]() {
#pragma unroll
    for (int u = 0; u < 3; ++u)
      if (sok[u]) *reinterpret_cast<float4*>(dst[u]) = rg[u];
  };

  // ---- compute-thread decode ----
  const int cr = tid / STRIPS;          // 0..5 for tid<240
  const int cs = tid - cr * STRIPS;
  const int w0 = cs * 4;
  const bool is_c = (tid < CTHREADS);

  auto ABC = [&](int t_, float A[4], float Bv[4], float Cv[4]) {
    float sw[3][4], dwv[3][4];
#pragma unroll
    for (int rr = 0; rr < 3; ++rr) {
      const float* row = &lds[t_][cr + rr][0];
      const float4 m = *reinterpret_cast<const float4*>(row + 4 + w0);
      const float xl = row[3 + w0], xr = row[8 + w0];
      const float x[6] = {xl, m.x, m.y, m.z, m.w, xr};
#pragma unroll
      for (int j = 0; j < 4; ++j) {
        sw[rr][j]  = x[j] + 2.f * x[j + 1] + x[j + 2];
        dwv[rr][j] = x[j + 2] - x[j];
      }
    }
#pragma unroll
    for (int j = 0; j < 4; ++j) {
      A[j]  = sw[0][j] + 2.f * sw[1][j] + sw[2][j];
      Bv[j] = dwv[0][j] + 2.f * dwv[1][j] + dwv[2][j];
      Cv[j] = sw[2][j] - sw[0][j];
    }
  };

  float pA0[4], pB0[4], pC0[4], pA1[4], pB1[4], pC1[4], pA2[4], pB2[4], pC2[4];
  float tA0[4], tB0[4], tC0[4], tA1[4], tB1[4], tC1[4], tA2[4], tB2[4], tC2[4];
  float acc = 0.f;

  // ---- prologue: slices d0-1 and d0 ----
  GLOAD(d0 - 1);
  DSW(); GLOAD(d0); __syncthreads();
  if (is_c) { ABC(0, pA0, pB0, pC0); ABC(1, tA0, tB0, tC0); }
  __syncthreads();
  DSW(); GLOAD(d0 + 1); __syncthreads();
  if (is_c) { ABC(0, pA1, pB1, pC1); ABC(1, tA1, tB1, tC1); }
  __syncthreads();

  // ---- main loop: output slice d0+k, consume slice d0+1+k, prefetch d0+2+k ----
  for (int k = 0; k < DCHUNK; ++k) {
    DSW();
    if (k < DCHUNK - 1) GLOAD(d0 + 2 + k);
    __syncthreads();
    if (is_c) {
      ABC(0, pA2, pB2, pC2); ABC(1, tA2, tB2, tC2);
#pragma unroll
      for (int j = 0; j < 4; ++j) {
        float gx = pB0[j] + 2.f * pB1[j] + pB2[j];
        float gy = pC0[j] + 2.f * pC1[j] + pC2[j];
        float gz = pA2[j] - pA0[j];
        const float pm = sqrtf(fmaf(gx, gx, fmaf(gy, gy, fmaf(gz, gz, EPS))));
        gx = tB0[j] + 2.f * tB1[j] + tB2[j];
        gy = tC0[j] + 2.f * tC1[j] + tC2[j];
        gz = tA2[j] - tA0[j];
        const float tm = sqrtf(fmaf(gx, gx, fmaf(gy, gy, fmaf(gz, gz, EPS))));
        acc += fabsf(pm - tm);
      }
#pragma unroll
      for (int j = 0; j < 4; ++j) {
        pA0[j] = pA1[j]; pB0[j] = pB1[j]; pC0[j] = pC1[j];
        pA1[j] = pA2[j]; pB1[j] = pB2[j]; pC1[j] = pC2[j];
        tA0[j] = tA1[j]; tB0[j] = tB1[j]; tC0[j] = tC1[j];
        tA1[j] = tA2[j]; tB1[j] = tB2[j]; tC1[j] = tC2[j];
      }
    }
    __syncthreads();
  }

  // ---- reduction: wave shfl -> LDS -> one atomic per block ----
  float s = acc;
#pragma unroll
  for (int off = 32; off > 0; off >>= 1) s += __shfl_down(s, off, 64);
  __shared__ float wsum[THREADS / 64];
  const int lane = tid & 63;
  const int wid = tid >> 6;
  if (lane == 0) wsum[wid] = s;
  __syncthreads();
  if (tid == 0) {
    float t = 0.f;
#pragma unroll
    for (int i = 0; i < THREADS / 64; ++i) t += wsum[i];
    atomicAdd(out, t * (1.0f / (float)((size_t)Bd * Dd * Hd * Wd)));
  }
}

extern "C" void kernel_launch(void* const* d_in, const int* in_sizes, int n_in,
                              void* d_out, int out_size, void* d_ws, size_t ws_size,
                              hipStream_t stream) {
  const float* pred = (const float*)d_in[0];
  const float* targ = (const float*)d_in[1];
  float* out = (float*)d_out;
  (void)in_sizes; (void)n_in; (void)out_size; (void)d_ws; (void)ws_size;

  hipMemsetAsync(out, 0, sizeof(float), stream);
  dim3 grid(RGROUPS, NCHUNK, Bd);
  sobel_loss_kernel<<<grid, THREADS, 0, stream>>>(pred, targ, out);
}